// Round 17
// baseline (428.775 us; speedup 1.0000x reference)
//
#include <hip/hip_runtime.h>
#include <math.h>

// B=2, C=128, H=W=64, N=4096.
// ws layout (bytes), 40 MiB:
//   [0,8M)   FQ bf16 split planes [p:rh,rl,ih,il][b][n][c]
//   [8,16M)  FK bf16 split planes (same)
//   [16,20M) FV bf16 planes [p:r,i][b][n][c]
//   [20,36M) spectra xr,xi,yr,yi fp32 (dead after proj)
//   [28,36M) Kpk frag-packed [b][mt(64)][a(4)][tml(4)][s(4)][l(64)][j(8)] (overlay yr/yi)
//   [36,40M) Vpk frag-packed [b][sm(128)][tc(16)][l(64)][j(8)]
//   [20,28M) Or_/Oi_ fp32 [b][n][c] (overlay dead xr/xi)
// frag map: lane l holds X[row=l&15][k=32s+8*(l>>4)+j]

#define PI2 6.283185307179586f

typedef __attribute__((ext_vector_type(8))) short short8;
typedef __attribute__((ext_vector_type(4))) float f32x4;

#define MFMA16(A,B,C) __builtin_amdgcn_mfma_f32_16x16x32_bf16((A),(B),(C),0,0,0)

__device__ inline unsigned short f2bf(float x){
  union{float f; unsigned int u;} a; a.f = x;
  unsigned int r = (a.u + 0x7fffu + ((a.u>>16)&1u)) >> 16;
  return (unsigned short)r;
}
__device__ inline float bf2f(unsigned short h){
  union{unsigned int u; float f;} a; a.u = ((unsigned int)h)<<16; return a.f;
}
__device__ inline short8 neg8(short8 x){
  union{short8 v; unsigned int u[4];} a; a.v = x;
  a.u[0]^=0x80008000u; a.u[1]^=0x80008000u; a.u[2]^=0x80008000u; a.u[3]^=0x80008000u;
  return a.v;
}
__device__ inline void gload_lds16(const void* g, void* lds){
  __builtin_amdgcn_global_load_lds((const __attribute__((address_space(1))) unsigned int*)g,
                                   (__attribute__((address_space(3))) unsigned int*)lds,
                                   16, 0, 0);
}

// ---------------------------------------------------------------------------
// Kernel 1: forward DFT2 of x and y
// ---------------------------------------------------------------------------
__global__ __launch_bounds__(256) void dft2_fwd_kernel(
    const float* __restrict__ x, const float* __restrict__ y,
    float* __restrict__ xr, float* __restrict__ xi,
    float* __restrict__ yr, float* __restrict__ yi)
{
  __shared__ float Xs[4096];
  __shared__ float Tr[4096], Ti[4096];
  __shared__ float twc[64], tws[64];
  int blk = blockIdx.x;
  const float* src; float *outr, *outi;
  int plane;
  if (blk < 256) { src = x; outr = xr; outi = xi; plane = blk; }
  else           { src = y; outr = yr; outi = yi; plane = blk - 256; }
  int b = plane >> 7, c = plane & 127;
  int t = threadIdx.x;
  if (t < 64) {
    float ang = -PI2 * (float)t / 64.0f;
    twc[t] = cosf(ang); tws[t] = sinf(ang);
  }
  const float* p = src + ((size_t)plane << 12);
  for (int i = t; i < 4096; i += 256) Xs[i] = p[i];
  __syncthreads();
  for (int j = 0; j < 16; j++) {
    int o = t + 256 * j; int h = o >> 6, wp = o & 63;
    float ar = 0.f, ai = 0.f;
    for (int w = 0; w < 64; w++) {
      int k = (w * wp) & 63;
      float v = Xs[h * 64 + w];
      ar = fmaf(v, twc[k], ar);
      ai = fmaf(v, tws[k], ai);
    }
    Tr[h * 64 + wp] = ar; Ti[h * 64 + wp] = ai;
  }
  __syncthreads();
  size_t ob = ((size_t)b * 4096) * 128 + c;
  for (int j = 0; j < 16; j++) {
    int o = t + 256 * j; int hp = o >> 6, wp = o & 63;
    float ar = 0.f, ai = 0.f;
    for (int h = 0; h < 64; h++) {
      int k = (h * hp) & 63;
      float cr = twc[k], ci = tws[k];
      float tr = Tr[h * 64 + wp], ti = Ti[h * 64 + wp];
      ar += tr * cr - ti * ci;
      ai += tr * ci + ti * cr;
    }
    int n = (hp << 6) + wp;
    outr[ob + (size_t)n * 128] = ar;
    outi[ob + (size_t)n * 128] = ai;
  }
}

// ---------------------------------------------------------------------------
// Kernel 2: complex projections -> flat bf16 split planes
// ---------------------------------------------------------------------------
__global__ __launch_bounds__(256) void proj_kernel(
    const float* __restrict__ xr, const float* __restrict__ xi,
    const float* __restrict__ yr, const float* __restrict__ yi,
    const float* __restrict__ Wqr, const float* __restrict__ bqr,
    const float* __restrict__ Wqi, const float* __restrict__ bqi,
    const float* __restrict__ Wkr, const float* __restrict__ bkr,
    const float* __restrict__ Wki, const float* __restrict__ bki,
    const float* __restrict__ Wvr, const float* __restrict__ bvr,
    const float* __restrict__ Wvi, const float* __restrict__ bvi,
    unsigned short* __restrict__ FQ, unsigned short* __restrict__ FK,
    unsigned short* __restrict__ FV)
{
  __shared__ float Asr[64 * 33], Asi[64 * 33], Wsr[128 * 33], Wsi[128 * 33];
  int nt = blockIdx.x, lin = blockIdx.y, b = blockIdx.z;
  const float *ar, *ai, *Wr, *Wi, *br_, *bi_;
  unsigned short* F;
  if (lin == 0)      { ar = xr; ai = xi; Wr = Wqr; Wi = Wqi; br_ = bqr; bi_ = bqi; F = FQ; }
  else if (lin == 1) { ar = yr; ai = yi; Wr = Wkr; Wi = Wki; br_ = bkr; bi_ = bki; F = FK; }
  else               { ar = yr; ai = yi; Wr = Wvr; Wi = Wvi; br_ = bvr; bi_ = bvi; F = FV; }
  int t = threadIdx.x; int td = t & 15, tn = t >> 4;
  int n0 = nt * 64;
  size_t abase = (size_t)b * 4096 * 128 + (size_t)n0 * 128;
  const size_t PS = (size_t)2 * 4096 * 128;
  float accr[4][8] = {}, acci[4][8] = {};
  for (int kk = 0; kk < 4; kk++) {
    __syncthreads();
    for (int idx = t; idx < 64 * 32; idx += 256) {
      int r = idx >> 5, ccol = idx & 31;
      Asr[r * 33 + ccol] = ar[abase + (size_t)r * 128 + kk * 32 + ccol];
      Asi[r * 33 + ccol] = ai[abase + (size_t)r * 128 + kk * 32 + ccol];
    }
    for (int idx = t; idx < 128 * 32; idx += 256) {
      int r = idx >> 5, ccol = idx & 31;
      Wsr[r * 33 + ccol] = Wr[(size_t)r * 128 + kk * 32 + ccol];
      Wsi[r * 33 + ccol] = Wi[(size_t)r * 128 + kk * 32 + ccol];
    }
    __syncthreads();
    for (int k = 0; k < 32; k++) {
      float a_r[4], a_i[4], w_r[8], w_i[8];
      #pragma unroll
      for (int i = 0; i < 4; i++) {
        a_r[i] = Asr[(tn * 4 + i) * 33 + k];
        a_i[i] = Asi[(tn * 4 + i) * 33 + k];
      }
      #pragma unroll
      for (int jj = 0; jj < 8; jj++) {
        w_r[jj] = Wsr[(td + 16 * jj) * 33 + k];
        w_i[jj] = Wsi[(td + 16 * jj) * 33 + k];
      }
      #pragma unroll
      for (int i = 0; i < 4; i++)
        #pragma unroll
        for (int jj = 0; jj < 8; jj++) {
          accr[i][jj] += a_r[i] * w_r[jj] - a_i[i] * w_i[jj];
          acci[i][jj] += a_i[i] * w_r[jj] + a_r[i] * w_i[jj];
        }
    }
  }
  for (int jj = 0; jj < 8; jj++) {
    int d = td + 16 * jj;
    float brd = br_[d], bid = bi_[d];
    #pragma unroll
    for (int i = 0; i < 4; i++) {
      int n = n0 + tn * 4 + i;
      float cr = accr[i][jj] + (brd - bid);
      float ci = acci[i][jj] + (brd + bid);
      size_t base = ((size_t)b * 4096 + n) * 128 + d;
      if (lin <= 1) {
        unsigned short rh = f2bf(cr); unsigned short rl = f2bf(cr - bf2f(rh));
        unsigned short ih = f2bf(ci); unsigned short il = f2bf(ci - bf2f(ih));
        F[0 * PS + base] = rh;
        F[1 * PS + base] = rl;
        F[2 * PS + base] = ih;
        F[3 * PS + base] = il;
      } else {
        F[0 * PS + base] = f2bf(cr);
        F[1 * PS + base] = f2bf(ci);
      }
    }
  }
}

// ---------------------------------------------------------------------------
// Kernel 2b: K pack to frag layout (pure permutation, write-coalesced)
// ---------------------------------------------------------------------------
__global__ __launch_bounds__(256) void kpack_kernel(
    const unsigned short* __restrict__ F, unsigned short* __restrict__ Kpk)
{
  int blk = blockIdx.x;                 // b*64 + mt
  int b = blk >> 6, mt = blk & 63;
  int t = threadIdx.x;
  size_t obase = (size_t)blk * 4096;    // short8 units per tile
  #pragma unroll
  for (int k = 0; k < 16; k++) {
    int idx = t + 256 * k;              // a(2)|tml(2)|s(2)|l(6)
    int l = idx & 63, s = (idx >> 6) & 3, tml = (idx >> 8) & 3, a = idx >> 10;
    int n = mt * 64 + tml * 16 + (l & 15);
    int c0 = 32 * s + 8 * (l >> 4);
    const short8 v = *(const short8*)(F + (((size_t)(a * 2 + b) * 4096 + n) * 128 + c0));
    *(short8*)(Kpk + (obase + idx) * 8) = v;
  }
}

// ---------------------------------------------------------------------------
// Kernel 2c: V pack (transpose to B-frag layout via LDS bounce)
// ---------------------------------------------------------------------------
__global__ __launch_bounds__(256) void vpack_kernel(
    const unsigned short* __restrict__ F, unsigned short* __restrict__ Vpk)
{
  __shared__ unsigned short Vs[2 * 32 * 128];
  int blk = blockIdx.x;
  int b = blk >> 7, sm = blk & 127;
  int t = threadIdx.x;
  const size_t PS = (size_t)2 * 4096 * 128;
  #pragma unroll
  for (int p = 0; p < 2; p++) {
    #pragma unroll
    for (int k = 0; k < 2; k++) {
      int idx8 = t + 256 * k;
      int nn = idx8 >> 4, d0 = (idx8 & 15) * 8;
      const short8 v = *(const short8*)(F + p * PS + ((size_t)(b * 4096 + sm * 32 + nn)) * 128 + d0);
      *(short8*)(Vs + (p * 32 + nn) * 128 + d0) = v;
    }
  }
  __syncthreads();
  size_t obase = (size_t)blk * 1024;
  #pragma unroll
  for (int k = 0; k < 4; k++) {
    int idx = t + 256 * k;
    int lv = idx & 63, tc = idx >> 6;
    int vh = tc >> 3;
    int d = (tc & 7) * 16 + (lv & 15);
    int nb = (lv >> 4) * 8;
    short8 v;
    #pragma unroll
    for (int j = 0; j < 8; j++)
      v[j] = (short)Vs[(vh * 32 + nb + j) * 128 + d];
    *(short8*)(Vpk + (obase + idx) * 8) = v;
  }
}

// ---------------------------------------------------------------------------
// Kernel 3: MFMA flash attention — single-barrier deferred pipeline (r17).
// Base = r15 (QBLK=16, 4 waves, 64KB K buffer, 2 blocks/CU, 4-chain QK,
// defer-rescale). New: pipeline deepened one stage so ONE barrier/iter
// publishes {Klds(mt+1), rmax(mt), Pfrag(mt-1)}. Pfrag/rmax parity-dbuf'd.
// STAGE uses wave-local channels (wave stages exactly what it reads).
// ---------------------------------------------------------------------------
__global__ __launch_bounds__(256, 2) void attn_mfma_kernel(
    const unsigned short* __restrict__ FQ, const short* __restrict__ Kpk,
    const short* __restrict__ Vpk,
    float* __restrict__ Or_, float* __restrict__ Oi_)
{
  __shared__ __align__(16) short Klds[32768];        // 64 KB, single buffer
  __shared__ __align__(16) short Pfrag2[2][16 * 72]; // parity dbuf
  __shared__ __align__(16) float rmax2[2][16][4];    // parity dbuf

  const int bi = blockIdx.x;
  const int xg = bi & 7;
  const int b = xg >> 2;                      // XCDs 0-3 -> b=0, 4-7 -> b=1
  const int qt2 = (bi >> 3) * 4 + (xg & 3);   // 0..255 (16-row q tile)
  const int t = threadIdx.x;
  const int ms = t >> 6, l = t & 63;
  const int g = l >> 4, c = l & 15;

  const size_t PS = (size_t)2 * 4096 * 128;
  short8 Qf[4][4];
  #pragma unroll
  for (int a = 0; a < 4; a++)
    #pragma unroll
    for (int s = 0; s < 4; s++)
      Qf[a][s] = *(const short8*)(FQ + (size_t)a * PS +
                 ((size_t)(b * 4096) + qt2 * 16 + c) * 128 + 32 * s + 8 * g);

  f32x4 O[4], Oe;
  #pragma unroll
  for (int nt = 0; nt < 4; nt++) O[nt] = (f32x4){0.f, 0.f, 0.f, 0.f};
  Oe = (f32x4){0.f, 0.f, 0.f, 0.f};
  float Mq = -3e38f, escPrev = 1.0f;
  bool upPrev = false;
  short8 Vreg[2][4];
  const short b1 = (short)0x3F80;
  const short8 ones = {b1, b1, b1, b1, b1, b1, b1, b1};
  const short8* Vp8 = (const short8*)Vpk;
  const short8* kb8 = (const short8*)Klds;

  // wave ms stages EXACTLY the channels it reads: ch = (a*4+ms)*4+s
  auto STAGE = [&](int tile) {
    const char* gsrc = (const char*)Kpk + ((size_t)(b * 64 + tile) << 16);
    #pragma unroll
    for (int a = 0; a < 4; a++)
      #pragma unroll
      for (int s = 0; s < 4; s++) {
        int ch = (a * 4 + ms) * 4 + s;
        gload_lds16(gsrc + ch * 1024 + l * 16, (char*)Klds + ch * 1024);
      }
  };
  // QK^T from LDS (4 independent accumulator chains), -> scores
  auto QK = [&](f32x4& sout) {
    f32x4 sr0 = (f32x4){0,0,0,0}, sr1 = (f32x4){0,0,0,0};
    f32x4 si0 = (f32x4){0,0,0,0}, si1 = (f32x4){0,0,0,0};
    __builtin_amdgcn_s_setprio(1);
    #pragma unroll
    for (int s = 0; s < 4; s++) {
      short8 Arh = kb8[((0 * 4 + ms) * 4 + s) * 64 + l];
      short8 Arl = kb8[((1 * 4 + ms) * 4 + s) * 64 + l];
      short8 Aih = kb8[((2 * 4 + ms) * 4 + s) * 64 + l];
      short8 Ail = kb8[((3 * 4 + ms) * 4 + s) * 64 + l];
      short8 nqh = neg8(Qf[2][s]);
      short8 nql = neg8(Qf[3][s]);
      f32x4& sr = (s & 1) ? sr1 : sr0;
      f32x4& si = (s & 1) ? si1 : si0;
      sr = MFMA16(Arh, Qf[0][s], sr);
      si = MFMA16(Arh, Qf[2][s], si);
      sr = MFMA16(Arh, Qf[1][s], sr);
      si = MFMA16(Arh, Qf[3][s], si);
      sr = MFMA16(Arl, Qf[0][s], sr);
      si = MFMA16(Arl, Qf[2][s], si);
      sr = MFMA16(Aih, nqh, sr);
      si = MFMA16(Aih, Qf[0][s], si);
      sr = MFMA16(Aih, nql, sr);
      si = MFMA16(Aih, Qf[1][s], si);
      sr = MFMA16(Ail, nqh, sr);
      si = MFMA16(Ail, Qf[0][s], si);
    }
    __builtin_amdgcn_s_setprio(0);
    #pragma unroll
    for (int r = 0; r < 4; r++) {
      float a2 = sr0[r] + sr1[r], b2 = si0[r] + si1[r];
      sout[r] = sqrtf(a2 * a2 + b2 * b2 + 1e-8f);
    }
  };
  auto WRMAX = [&](const f32x4& s0, int par) {
    float mloc = fmaxf(fmaxf(s0[0], s0[1]), fmaxf(s0[2], s0[3]));
    mloc = fmaxf(mloc, __shfl_xor(mloc, 16));
    mloc = fmaxf(mloc, __shfl_xor(mloc, 32));
    if (l < 16) rmax2[par][l][ms] = mloc;
  };
  auto LOADV = [&](int mt) {
    #pragma unroll
    for (int ks = 0; ks < 2; ks++)
      #pragma unroll
      for (int nt = 0; nt < 4; nt++)
        Vreg[ks][nt] = Vp8[((size_t)((b * 128 + mt * 2 + ks) * 16 + ms * 4 + nt)) * 64 + l];
  };
  auto RESCALE = [&]() {
    f32x4 esc4;
    #pragma unroll
    for (int r = 0; r < 4; r++) esc4[r] = __shfl(escPrev, 4 * g + r);
    #pragma unroll
    for (int r = 0; r < 4; r++) {
      #pragma unroll
      for (int nt = 0; nt < 4; nt++) O[nt][r] *= esc4[r];
      Oe[r] *= esc4[r];
    }
  };
  auto PV = [&](int par) {
    __builtin_amdgcn_s_setprio(1);
    #pragma unroll
    for (int ks = 0; ks < 2; ks++) {
      short8 Pa = *(const short8*)&Pfrag2[par][c * 72 + 32 * ks + 8 * g];
      #pragma unroll
      for (int nt = 0; nt < 4; nt++)
        O[nt] = MFMA16(Pa, Vreg[ks][nt], O[nt]);
      Oe = MFMA16(Pa, ones, Oe);
    }
    __builtin_amdgcn_s_setprio(0);
  };
  // softmax for tile whose rmax lives in rmax2[par]; packs P into Pfrag2[par]
  auto SOFTMAX = [&](const f32x4& sPrev, int par) {
    f32x4 rm4 = *(const f32x4*)&rmax2[par][c][0];
    float cand = fmaxf(fmaxf(rm4[0], rm4[1]), fmaxf(rm4[2], rm4[3]));
    bool up = !__all((int)(cand <= Mq + 8.0f));
    if (up) {
      float Mnew = fmaxf(Mq, cand);
      escPrev = __expf(Mq - Mnew);
      Mq = Mnew;
    }
    upPrev = up;
    f32x4 p;
    #pragma unroll
    for (int r = 0; r < 4; r++) p[r] = __expf(sPrev[r] - Mq);
    unsigned int* pw = (unsigned int*)&Pfrag2[par][c * 72 + 16 * ms + 4 * g];
    pw[0] = (unsigned int)f2bf(p[0]) | ((unsigned int)f2bf(p[1]) << 16);
    pw[1] = (unsigned int)f2bf(p[2]) | ((unsigned int)f2bf(p[3]) << 16);
  };

  STAGE(0);
  asm volatile("s_waitcnt vmcnt(0)" ::: "memory");
  __builtin_amdgcn_s_barrier();
  __builtin_amdgcn_sched_barrier(0);

  f32x4 s0prev, s0new;
  // ---- peeled iter mt=0: QK(0), STAGE(1), rmax(0) ----
  QK(s0prev);
  asm volatile("s_waitcnt lgkmcnt(0)" ::: "memory");
  __builtin_amdgcn_sched_barrier(0);
  STAGE(1);
  __builtin_amdgcn_sched_barrier(0);
  WRMAX(s0prev, 0);
  asm volatile("s_waitcnt vmcnt(0) lgkmcnt(0)" ::: "memory");
  __builtin_amdgcn_s_barrier();
  __builtin_amdgcn_sched_barrier(0);

  // ---- main loop mt = 1..63 (single barrier per iteration) ----
  for (int mt = 1; mt < 64; mt++) {
    const int p = mt & 1;
    // 1. QK(mt) from Klds
    QK(s0new);
    asm volatile("s_waitcnt lgkmcnt(0)" ::: "memory");   // own K reads retired
    __builtin_amdgcn_sched_barrier(0);
    // 2. stage next tile into wave-local channels (long window)
    if (mt + 1 < 64) STAGE(mt + 1);
    __builtin_amdgcn_sched_barrier(0);
    // 3. PV(mt-2): Pfrag2[p], Vreg, esc(mt-2)
    if (mt >= 2) {
      if (upPrev) RESCALE();
      PV(p);
    }
    // 4. V(mt-1) loads (consumed by PV(mt-1) next iter)
    LOADV(mt - 1);
    __builtin_amdgcn_sched_barrier(0);
    // 5. softmax(mt-1): rmax2[p^1], s0prev -> Pfrag2[p^1], esc/up for mt-1
    SOFTMAX(s0prev, p ^ 1);
    // 6. rmax(mt) -> rmax2[p]
    WRMAX(s0new, p);
    s0prev = s0new;
    // 7. single barrier: drain 16 K-DMA (keep 8 V loads), publish LDS
    __builtin_amdgcn_sched_barrier(0);
    asm volatile("s_waitcnt vmcnt(8) lgkmcnt(0)" ::: "memory");
    __builtin_amdgcn_s_barrier();
    __builtin_amdgcn_sched_barrier(0);
  }

  // ---- epilogue ----
  // state: s0prev=s0(63); Pfrag2[0]=P(62); Vreg=V(62); esc/up for 62;
  //        rmax2[1]=rmax(63); Mq = M_62.
  if (upPrev) RESCALE();
  PV(0);                         // PV(62)
  LOADV(63);
  SOFTMAX(s0prev, 1);            // tile 63 -> Pfrag2[1], esc/up for 63
  asm volatile("s_waitcnt lgkmcnt(0)" ::: "memory");
  __builtin_amdgcn_s_barrier();
  __builtin_amdgcn_sched_barrier(0);
  if (upPrev) RESCALE();
  PV(1);                         // PV(63)

  // ---- normalize + write out (row q = 4g+r, cc = ms*64 + nt*16 + c) ----
  const size_t base = (size_t)b * 4096 * 128;
  f32x4 inv;
  #pragma unroll
  for (int r = 0; r < 4; r++) inv[r] = 1.0f / Oe[r];
  #pragma unroll
  for (int nt = 0; nt < 4; nt++) {
    int cc = ms * 64 + nt * 16 + c;
    #pragma unroll
    for (int r = 0; r < 4; r++) {
      int row = qt2 * 16 + 4 * g + r;
      float v = O[nt][r] * inv[r];
      if (cc < 128) Or_[base + (size_t)row * 128 + cc] = v;
      else          Oi_[base + (size_t)row * 128 + cc - 128] = v;
    }
  }
}

// ---------------------------------------------------------------------------
// Kernel 4: inverse DFT2 (real part), output [b][c][h][w]
// ---------------------------------------------------------------------------
__global__ __launch_bounds__(256) void idft2_kernel(
    const float* __restrict__ Or_, const float* __restrict__ Oi_,
    float* __restrict__ out)
{
  __shared__ float Ar[4096], Ai[4096], Tr[4096], Ti[4096];
  __shared__ float twc[64], tws[64];
  int plane = blockIdx.x; int b = plane >> 7, c = plane & 127;
  int t = threadIdx.x;
  if (t < 64) {
    float ang = PI2 * (float)t / 64.0f;
    twc[t] = cosf(ang); tws[t] = sinf(ang);
  }
  size_t ibase = (size_t)b * 4096 * 128 + c;
  for (int i = t; i < 4096; i += 256) {
    Ar[i] = Or_[ibase + (size_t)i * 128];
    Ai[i] = Oi_[ibase + (size_t)i * 128];
  }
  __syncthreads();
  for (int j = 0; j < 16; j++) {
    int o = t + 256 * j; int hp = o >> 6, w = o & 63;
    float tr = 0.f, ti = 0.f;
    for (int wp = 0; wp < 64; wp++) {
      int k = (wp * w) & 63;
      float cr = twc[k], ci = tws[k];
      float ar = Ar[hp * 64 + wp], ai = Ai[hp * 64 + wp];
      tr += ar * cr - ai * ci;
      ti += ai * cr + ar * ci;
    }
    Tr[hp * 64 + w] = tr; Ti[hp * 64 + w] = ti;
  }
  __syncthreads();
  size_t obase = ((size_t)plane) << 12;
  for (int j = 0; j < 16; j++) {
    int o = t + 256 * j; int h = o >> 6, w = o & 63;
    float acc = 0.f;
    for (int hp = 0; hp < 64; hp++) {
      int k = (hp * h) & 63;
      acc += Tr[hp * 64 + w] * twc[k] - Ti[hp * 64 + w] * tws[k];
    }
    out[obase + o] = acc * (1.0f / 4096.0f);
  }
}

extern "C" void kernel_launch(void* const* d_in, const int* in_sizes, int n_in,
                              void* d_out, int out_size, void* d_ws, size_t ws_size,
                              hipStream_t stream) {
  const float* x   = (const float*)d_in[0];
  const float* y   = (const float*)d_in[1];
  const float* Wqr = (const float*)d_in[2];  const float* bqr = (const float*)d_in[3];
  const float* Wqi = (const float*)d_in[4];  const float* bqi = (const float*)d_in[5];
  const float* Wkr = (const float*)d_in[6];  const float* bkr = (const float*)d_in[7];
  const float* Wki = (const float*)d_in[8];  const float* bki = (const float*)d_in[9];
  const float* Wvr = (const float*)d_in[10]; const float* bvr = (const float*)d_in[11];
  const float* Wvi = (const float*)d_in[12]; const float* bvi = (const float*)d_in[13];
  char* wsb = (char*)d_ws;
  if (ws_size < ((size_t)40 << 20)) return;  // need 40 MiB
  unsigned short* FQ  = (unsigned short*)(wsb);                      // [0,8M)
  unsigned short* FK  = (unsigned short*)(wsb + ((size_t)8  << 20)); // [8,16M)
  unsigned short* FV  = (unsigned short*)(wsb + ((size_t)16 << 20)); // [16,20M)
  float* xr = (float*)(wsb + ((size_t)20 << 20));
  float* xi = (float*)(wsb + ((size_t)24 << 20));
  float* yr = (float*)(wsb + ((size_t)28 << 20));
  float* yi = (float*)(wsb + ((size_t)32 << 20));
  unsigned short* Kpk = (unsigned short*)(wsb + ((size_t)28 << 20)); // overlay dead yr/yi
  unsigned short* Vpk = (unsigned short*)(wsb + ((size_t)36 << 20)); // [36,40M)
  float* Or_ = (float*)(wsb + ((size_t)20 << 20));  // overlay dead xr
  float* Oi_ = (float*)(wsb + ((size_t)24 << 20));  // overlay dead xi
  float* out = (float*)d_out;

  hipLaunchKernelGGL(dft2_fwd_kernel, dim3(512), dim3(256), 0, stream,
                     x, y, xr, xi, yr, yi);
  hipLaunchKernelGGL(proj_kernel, dim3(64, 3, 2), dim3(256), 0, stream,
                     xr, xi, yr, yi,
                     Wqr, bqr, Wqi, bqi, Wkr, bkr, Wki, bki, Wvr, bvr, Wvi, bvi,
                     FQ, FK, FV);
  hipLaunchKernelGGL(kpack_kernel, dim3(128), dim3(256), 0, stream, FK, Kpk);
  hipLaunchKernelGGL(vpack_kernel, dim3(256), dim3(256), 0, stream, FV, Vpk);
  hipLaunchKernelGGL(attn_mfma_kernel, dim3(512), dim3(256), 0, stream,
                     FQ, (const short*)Kpk, (const short*)Vpk, Or_, Oi_);
  hipLaunchKernelGGL(idft2_kernel, dim3(256), dim3(256), 0, stream,
                     Or_, Oi_, out);
}

// Round 18
// 404.675 us; speedup vs baseline: 1.0596x; 1.0596x over previous
//
#include <hip/hip_runtime.h>
#include <math.h>

// B=2, C=128, H=W=64, N=4096.
// ws layout (bytes), 40 MiB:
//   [0,8M)   FQ bf16 split planes [p:rh,rl,ih,il][b][n][c]
//   [8,16M)  FK bf16 split planes (same)
//   [16,20M) FV bf16 planes [p:r,i][b][n][c]
//   [20,36M) spectra xr,xi,yr,yi fp32 (dead after proj)
//   [28,36M) Kpk frag-packed [b][mt(64)][a(4)][tml(4)][s(4)][l(64)][j(8)] (overlay yr/yi)
//   [36,40M) Vpk frag-packed [b][sm(128)][tc(16)][l(64)][j(8)]
//   [20,28M) Or_/Oi_ fp32 [b][n][c] (overlay dead xr/xi)
// frag map: lane l holds X[row=l&15][k=32s+8*(l>>4)+j]

#define PI2 6.283185307179586f

typedef __attribute__((ext_vector_type(8))) short short8;
typedef __attribute__((ext_vector_type(4))) float f32x4;

#define MFMA16(A,B,C) __builtin_amdgcn_mfma_f32_16x16x32_bf16((A),(B),(C),0,0,0)

__device__ inline unsigned short f2bf(float x){
  union{float f; unsigned int u;} a; a.f = x;
  unsigned int r = (a.u + 0x7fffu + ((a.u>>16)&1u)) >> 16;
  return (unsigned short)r;
}
__device__ inline float bf2f(unsigned short h){
  union{unsigned int u; float f;} a; a.u = ((unsigned int)h)<<16; return a.f;
}
__device__ inline short8 neg8(short8 x){
  union{short8 v; unsigned int u[4];} a; a.v = x;
  a.u[0]^=0x80008000u; a.u[1]^=0x80008000u; a.u[2]^=0x80008000u; a.u[3]^=0x80008000u;
  return a.v;
}
__device__ inline void gload_lds16(const void* g, void* lds){
  __builtin_amdgcn_global_load_lds((const __attribute__((address_space(1))) unsigned int*)g,
                                   (__attribute__((address_space(3))) unsigned int*)lds,
                                   16, 0, 0);
}

// ---------------------------------------------------------------------------
// Kernel 1: forward DFT2 of x and y
// ---------------------------------------------------------------------------
__global__ __launch_bounds__(256) void dft2_fwd_kernel(
    const float* __restrict__ x, const float* __restrict__ y,
    float* __restrict__ xr, float* __restrict__ xi,
    float* __restrict__ yr, float* __restrict__ yi)
{
  __shared__ float Xs[4096];
  __shared__ float Tr[4096], Ti[4096];
  __shared__ float twc[64], tws[64];
  int blk = blockIdx.x;
  const float* src; float *outr, *outi;
  int plane;
  if (blk < 256) { src = x; outr = xr; outi = xi; plane = blk; }
  else           { src = y; outr = yr; outi = yi; plane = blk - 256; }
  int b = plane >> 7, c = plane & 127;
  int t = threadIdx.x;
  if (t < 64) {
    float ang = -PI2 * (float)t / 64.0f;
    twc[t] = cosf(ang); tws[t] = sinf(ang);
  }
  const float* p = src + ((size_t)plane << 12);
  for (int i = t; i < 4096; i += 256) Xs[i] = p[i];
  __syncthreads();
  for (int j = 0; j < 16; j++) {
    int o = t + 256 * j; int h = o >> 6, wp = o & 63;
    float ar = 0.f, ai = 0.f;
    for (int w = 0; w < 64; w++) {
      int k = (w * wp) & 63;
      float v = Xs[h * 64 + w];
      ar = fmaf(v, twc[k], ar);
      ai = fmaf(v, tws[k], ai);
    }
    Tr[h * 64 + wp] = ar; Ti[h * 64 + wp] = ai;
  }
  __syncthreads();
  size_t ob = ((size_t)b * 4096) * 128 + c;
  for (int j = 0; j < 16; j++) {
    int o = t + 256 * j; int hp = o >> 6, wp = o & 63;
    float ar = 0.f, ai = 0.f;
    for (int h = 0; h < 64; h++) {
      int k = (h * hp) & 63;
      float cr = twc[k], ci = tws[k];
      float tr = Tr[h * 64 + wp], ti = Ti[h * 64 + wp];
      ar += tr * cr - ti * ci;
      ai += tr * ci + ti * cr;
    }
    int n = (hp << 6) + wp;
    outr[ob + (size_t)n * 128] = ar;
    outi[ob + (size_t)n * 128] = ai;
  }
}

// ---------------------------------------------------------------------------
// Kernel 2: complex projections -> flat bf16 split planes
// ---------------------------------------------------------------------------
__global__ __launch_bounds__(256) void proj_kernel(
    const float* __restrict__ xr, const float* __restrict__ xi,
    const float* __restrict__ yr, const float* __restrict__ yi,
    const float* __restrict__ Wqr, const float* __restrict__ bqr,
    const float* __restrict__ Wqi, const float* __restrict__ bqi,
    const float* __restrict__ Wkr, const float* __restrict__ bkr,
    const float* __restrict__ Wki, const float* __restrict__ bki,
    const float* __restrict__ Wvr, const float* __restrict__ bvr,
    const float* __restrict__ Wvi, const float* __restrict__ bvi,
    unsigned short* __restrict__ FQ, unsigned short* __restrict__ FK,
    unsigned short* __restrict__ FV)
{
  __shared__ float Asr[64 * 33], Asi[64 * 33], Wsr[128 * 33], Wsi[128 * 33];
  int nt = blockIdx.x, lin = blockIdx.y, b = blockIdx.z;
  const float *ar, *ai, *Wr, *Wi, *br_, *bi_;
  unsigned short* F;
  if (lin == 0)      { ar = xr; ai = xi; Wr = Wqr; Wi = Wqi; br_ = bqr; bi_ = bqi; F = FQ; }
  else if (lin == 1) { ar = yr; ai = yi; Wr = Wkr; Wi = Wki; br_ = bkr; bi_ = bki; F = FK; }
  else               { ar = yr; ai = yi; Wr = Wvr; Wi = Wvi; br_ = bvr; bi_ = bvi; F = FV; }
  int t = threadIdx.x; int td = t & 15, tn = t >> 4;
  int n0 = nt * 64;
  size_t abase = (size_t)b * 4096 * 128 + (size_t)n0 * 128;
  const size_t PS = (size_t)2 * 4096 * 128;
  float accr[4][8] = {}, acci[4][8] = {};
  for (int kk = 0; kk < 4; kk++) {
    __syncthreads();
    for (int idx = t; idx < 64 * 32; idx += 256) {
      int r = idx >> 5, ccol = idx & 31;
      Asr[r * 33 + ccol] = ar[abase + (size_t)r * 128 + kk * 32 + ccol];
      Asi[r * 33 + ccol] = ai[abase + (size_t)r * 128 + kk * 32 + ccol];
    }
    for (int idx = t; idx < 128 * 32; idx += 256) {
      int r = idx >> 5, ccol = idx & 31;
      Wsr[r * 33 + ccol] = Wr[(size_t)r * 128 + kk * 32 + ccol];
      Wsi[r * 33 + ccol] = Wi[(size_t)r * 128 + kk * 32 + ccol];
    }
    __syncthreads();
    for (int k = 0; k < 32; k++) {
      float a_r[4], a_i[4], w_r[8], w_i[8];
      #pragma unroll
      for (int i = 0; i < 4; i++) {
        a_r[i] = Asr[(tn * 4 + i) * 33 + k];
        a_i[i] = Asi[(tn * 4 + i) * 33 + k];
      }
      #pragma unroll
      for (int jj = 0; jj < 8; jj++) {
        w_r[jj] = Wsr[(td + 16 * jj) * 33 + k];
        w_i[jj] = Wsi[(td + 16 * jj) * 33 + k];
      }
      #pragma unroll
      for (int i = 0; i < 4; i++)
        #pragma unroll
        for (int jj = 0; jj < 8; jj++) {
          accr[i][jj] += a_r[i] * w_r[jj] - a_i[i] * w_i[jj];
          acci[i][jj] += a_i[i] * w_r[jj] + a_r[i] * w_i[jj];
        }
    }
  }
  for (int jj = 0; jj < 8; jj++) {
    int d = td + 16 * jj;
    float brd = br_[d], bid = bi_[d];
    #pragma unroll
    for (int i = 0; i < 4; i++) {
      int n = n0 + tn * 4 + i;
      float cr = accr[i][jj] + (brd - bid);
      float ci = acci[i][jj] + (brd + bid);
      size_t base = ((size_t)b * 4096 + n) * 128 + d;
      if (lin <= 1) {
        unsigned short rh = f2bf(cr); unsigned short rl = f2bf(cr - bf2f(rh));
        unsigned short ih = f2bf(ci); unsigned short il = f2bf(ci - bf2f(ih));
        F[0 * PS + base] = rh;
        F[1 * PS + base] = rl;
        F[2 * PS + base] = ih;
        F[3 * PS + base] = il;
      } else {
        F[0 * PS + base] = f2bf(cr);
        F[1 * PS + base] = f2bf(ci);
      }
    }
  }
}

// ---------------------------------------------------------------------------
// Kernel 2b: K pack to frag layout (pure permutation, write-coalesced)
// ---------------------------------------------------------------------------
__global__ __launch_bounds__(256) void kpack_kernel(
    const unsigned short* __restrict__ F, unsigned short* __restrict__ Kpk)
{
  int blk = blockIdx.x;                 // b*64 + mt
  int b = blk >> 6, mt = blk & 63;
  int t = threadIdx.x;
  size_t obase = (size_t)blk * 4096;    // short8 units per tile
  #pragma unroll
  for (int k = 0; k < 16; k++) {
    int idx = t + 256 * k;              // a(2)|tml(2)|s(2)|l(6)
    int l = idx & 63, s = (idx >> 6) & 3, tml = (idx >> 8) & 3, a = idx >> 10;
    int n = mt * 64 + tml * 16 + (l & 15);
    int c0 = 32 * s + 8 * (l >> 4);
    const short8 v = *(const short8*)(F + (((size_t)(a * 2 + b) * 4096 + n) * 128 + c0));
    *(short8*)(Kpk + (obase + idx) * 8) = v;
  }
}

// ---------------------------------------------------------------------------
// Kernel 2c: V pack (transpose to B-frag layout via LDS bounce)
// ---------------------------------------------------------------------------
__global__ __launch_bounds__(256) void vpack_kernel(
    const unsigned short* __restrict__ F, unsigned short* __restrict__ Vpk)
{
  __shared__ unsigned short Vs[2 * 32 * 128];
  int blk = blockIdx.x;
  int b = blk >> 7, sm = blk & 127;
  int t = threadIdx.x;
  const size_t PS = (size_t)2 * 4096 * 128;
  #pragma unroll
  for (int p = 0; p < 2; p++) {
    #pragma unroll
    for (int k = 0; k < 2; k++) {
      int idx8 = t + 256 * k;
      int nn = idx8 >> 4, d0 = (idx8 & 15) * 8;
      const short8 v = *(const short8*)(F + p * PS + ((size_t)(b * 4096 + sm * 32 + nn)) * 128 + d0);
      *(short8*)(Vs + (p * 32 + nn) * 128 + d0) = v;
    }
  }
  __syncthreads();
  size_t obase = (size_t)blk * 1024;
  #pragma unroll
  for (int k = 0; k < 4; k++) {
    int idx = t + 256 * k;
    int lv = idx & 63, tc = idx >> 6;
    int vh = tc >> 3;
    int d = (tc & 7) * 16 + (lv & 15);
    int nb = (lv >> 4) * 8;
    short8 v;
    #pragma unroll
    for (int j = 0; j < 8; j++)
      v[j] = (short)Vs[(vh * 32 + nb + j) * 128 + d];
    *(short8*)(Vpk + (obase + idx) * 8) = v;
  }
}

// ---------------------------------------------------------------------------
// Kernel 3: MFMA flash attention (r15 — best known configuration).
// QBLK=16, 4 waves, single 64KB K buffer, 2 blocks/CU.
// 4 independent QK accumulator chains + defer-rescale (T13, THR=8).
// Proven vmcnt(8) accounting at 104 VGPR (no spill hazard).
// ---------------------------------------------------------------------------
__global__ __launch_bounds__(256, 2) void attn_mfma_kernel(
    const unsigned short* __restrict__ FQ, const short* __restrict__ Kpk,
    const short* __restrict__ Vpk,
    float* __restrict__ Or_, float* __restrict__ Oi_)
{
  __shared__ __align__(16) short Klds[32768];      // 64 KB, single buffer
  __shared__ __align__(16) short Pfrag[16 * 72];   // [q][64m + 8 pad]
  __shared__ __align__(16) float rmax[16][4];      // [q][ms]

  const int bi = blockIdx.x;
  const int xg = bi & 7;
  const int b = xg >> 2;                      // XCDs 0-3 -> b=0, 4-7 -> b=1
  const int qt2 = (bi >> 3) * 4 + (xg & 3);   // 0..255 (16-row q tile)
  const int t = threadIdx.x;
  const int ms = t >> 6, l = t & 63;
  const int g = l >> 4, c = l & 15;

  const size_t PS = (size_t)2 * 4096 * 128;
  // Q frags (B-operand): lane l holds Q[q=c][k=32s+8g+j], 16 loads once
  short8 Qf[4][4];
  #pragma unroll
  for (int a = 0; a < 4; a++)
    #pragma unroll
    for (int s = 0; s < 4; s++)
      Qf[a][s] = *(const short8*)(FQ + (size_t)a * PS +
                 ((size_t)(b * 4096) + qt2 * 16 + c) * 128 + 32 * s + 8 * g);

  f32x4 O[4], Oe;
  #pragma unroll
  for (int nt = 0; nt < 4; nt++) O[nt] = (f32x4){0.f, 0.f, 0.f, 0.f};
  Oe = (f32x4){0.f, 0.f, 0.f, 0.f};
  float Mq = -3e38f, escPrev = 1.0f;
  bool upPrev = false;
  short8 Vreg[2][4];
  const short b1 = (short)0x3F80;
  const short8 ones = {b1, b1, b1, b1, b1, b1, b1, b1};
  const short8* Vp8 = (const short8*)Vpk;

  auto STAGE = [&](int tile) {
    const char* gsrc = (const char*)Kpk + ((size_t)(b * 64 + tile) << 16);
    #pragma unroll
    for (int i2 = 0; i2 < 16; i2++) {
      int ch = ms * 16 + i2;
      gload_lds16(gsrc + ch * 1024 + l * 16, (char*)Klds + ch * 1024);
    }
  };

  STAGE(0);
  asm volatile("s_waitcnt vmcnt(0)" ::: "memory");
  __builtin_amdgcn_s_barrier();
  __builtin_amdgcn_sched_barrier(0);

  f32x4 s0;
  for (int mt = 0; mt < 64; mt++) {
    // ---- PV(mt-1): (deferred) rescale + accumulate (no K-LDS access) ----
    if (mt > 0) {
      if (upPrev) {
        f32x4 esc4;
        #pragma unroll
        for (int r = 0; r < 4; r++) esc4[r] = __shfl(escPrev, 4 * g + r);
        #pragma unroll
        for (int r = 0; r < 4; r++) {
          #pragma unroll
          for (int nt = 0; nt < 4; nt++) O[nt][r] *= esc4[r];
          Oe[r] *= esc4[r];
        }
      }
      __builtin_amdgcn_s_setprio(1);
      #pragma unroll
      for (int ks = 0; ks < 2; ks++) {
        short8 Pa = *(const short8*)&Pfrag[c * 72 + 32 * ks + 8 * g];
        #pragma unroll
        for (int nt = 0; nt < 4; nt++)
          O[nt] = MFMA16(Pa, Vreg[ks][nt], O[nt]);
        Oe = MFMA16(Pa, ones, Oe);
      }
      __builtin_amdgcn_s_setprio(0);
    }
    // ---- QK^T(mt) on this wave's 16-m slice, split bf16 hh+hl+lh,
    //      4 independent accumulator chains (s-parity) ----
    const short8* kb8 = (const short8*)Klds;
    f32x4 sr0 = (f32x4){0,0,0,0}, sr1 = (f32x4){0,0,0,0};
    f32x4 si0 = (f32x4){0,0,0,0}, si1 = (f32x4){0,0,0,0};
    __builtin_amdgcn_s_setprio(1);
    #pragma unroll
    for (int s = 0; s < 4; s++) {
      short8 Arh = kb8[((0 * 4 + ms) * 4 + s) * 64 + l];
      short8 Arl = kb8[((1 * 4 + ms) * 4 + s) * 64 + l];
      short8 Aih = kb8[((2 * 4 + ms) * 4 + s) * 64 + l];
      short8 Ail = kb8[((3 * 4 + ms) * 4 + s) * 64 + l];
      short8 nqh = neg8(Qf[2][s]);
      short8 nql = neg8(Qf[3][s]);
      f32x4& sr = (s & 1) ? sr1 : sr0;
      f32x4& si = (s & 1) ? si1 : si0;
      sr = MFMA16(Arh, Qf[0][s], sr);
      si = MFMA16(Arh, Qf[2][s], si);
      sr = MFMA16(Arh, Qf[1][s], sr);
      si = MFMA16(Arh, Qf[3][s], si);
      sr = MFMA16(Arl, Qf[0][s], sr);
      si = MFMA16(Arl, Qf[2][s], si);
      sr = MFMA16(Aih, nqh, sr);
      si = MFMA16(Aih, Qf[0][s], si);
      sr = MFMA16(Aih, nql, sr);
      si = MFMA16(Aih, Qf[1][s], si);
      sr = MFMA16(Ail, nqh, sr);
      si = MFMA16(Ail, Qf[0][s], si);
    }
    __builtin_amdgcn_s_setprio(0);
    // ---- scores + slice-max (lane: m=16ms+4g+r, q=c) ----
    #pragma unroll
    for (int r = 0; r < 4; r++) {
      float a2 = sr0[r] + sr1[r], b2 = si0[r] + si1[r];
      s0[r] = sqrtf(a2 * a2 + b2 * b2 + 1e-8f);
    }
    float mloc = fmaxf(fmaxf(s0[0], s0[1]), fmaxf(s0[2], s0[3]));
    mloc = fmaxf(mloc, __shfl_xor(mloc, 16));
    mloc = fmaxf(mloc, __shfl_xor(mloc, 32));
    if (l < 16) rmax[l][ms] = mloc;
    // SYNC B: all QK reads of tile mt retired; rmax visible
    asm volatile("s_waitcnt lgkmcnt(0)" ::: "memory");
    __builtin_amdgcn_s_barrier();
    __builtin_amdgcn_sched_barrier(0);
    // safe now to overwrite the K buffer: issue DMA for tile mt+1
    if (mt + 1 < 64) STAGE(mt + 1);
    {
      f32x4 rm4 = *(const f32x4*)&rmax[c][0];
      float cand = fmaxf(fmaxf(rm4[0], rm4[1]), fmaxf(rm4[2], rm4[3]));
      // defer-rescale: update running max only if some q grew by > 8
      bool up = !__all((int)(cand <= Mq + 8.0f));
      if (up) {
        float Mnew = fmaxf(Mq, cand);
        escPrev = __expf(Mq - Mnew);
        Mq = Mnew;
      }
      upPrev = up;
      f32x4 p;
      #pragma unroll
      for (int r = 0; r < 4; r++) p[r] = __expf(s0[r] - Mq);
      unsigned int* pw = (unsigned int*)&Pfrag[c * 72 + 16 * ms + 4 * g];
      pw[0] = (unsigned int)f2bf(p[0]) | ((unsigned int)f2bf(p[1]) << 16);
      pw[1] = (unsigned int)f2bf(p[2]) | ((unsigned int)f2bf(p[3]) << 16);
      // V(mt) prefetch for PV at iter mt+1 (stays in flight across SYNC A)
      #pragma unroll
      for (int ks = 0; ks < 2; ks++)
        #pragma unroll
        for (int nt = 0; nt < 4; nt++)
          Vreg[ks][nt] = Vp8[((size_t)((b * 128 + mt * 2 + ks) * 16 + ms * 4 + nt)) * 64 + l];
    }
    // SYNC A: vmcnt(8) drains the 16 K-DMA ops, leaves the 8 V loads;
    // lgkmcnt(0) makes Pfrag visible.
    __builtin_amdgcn_sched_barrier(0);
    asm volatile("s_waitcnt vmcnt(8) lgkmcnt(0)" ::: "memory");
    __builtin_amdgcn_s_barrier();
    __builtin_amdgcn_sched_barrier(0);
  }
  // ---- tail PV(63) ----
  {
    if (upPrev) {
      f32x4 esc4;
      #pragma unroll
      for (int r = 0; r < 4; r++) esc4[r] = __shfl(escPrev, 4 * g + r);
      #pragma unroll
      for (int r = 0; r < 4; r++) {
        #pragma unroll
        for (int nt = 0; nt < 4; nt++) O[nt][r] *= esc4[r];
        Oe[r] *= esc4[r];
      }
    }
    #pragma unroll
    for (int ks = 0; ks < 2; ks++) {
      short8 Pa = *(const short8*)&Pfrag[c * 72 + 32 * ks + 8 * g];
      #pragma unroll
      for (int nt = 0; nt < 4; nt++)
        O[nt] = MFMA16(Pa, Vreg[ks][nt], O[nt]);
      Oe = MFMA16(Pa, ones, Oe);
    }
  }
  // ---- normalize + write out (row q = 4g+r, cc = ms*64 + nt*16 + c) ----
  const size_t base = (size_t)b * 4096 * 128;
  f32x4 inv;
  #pragma unroll
  for (int r = 0; r < 4; r++) inv[r] = 1.0f / Oe[r];
  #pragma unroll
  for (int nt = 0; nt < 4; nt++) {
    int cc = ms * 64 + nt * 16 + c;
    #pragma unroll
    for (int r = 0; r < 4; r++) {
      int row = qt2 * 16 + 4 * g + r;
      float v = O[nt][r] * inv[r];
      if (cc < 128) Or_[base + (size_t)row * 128 + cc] = v;
      else          Oi_[base + (size_t)row * 128 + cc - 128] = v;
    }
  }
}

// ---------------------------------------------------------------------------
// Kernel 4: inverse DFT2 (real part), output [b][c][h][w]
// ---------------------------------------------------------------------------
__global__ __launch_bounds__(256) void idft2_kernel(
    const float* __restrict__ Or_, const float* __restrict__ Oi_,
    float* __restrict__ out)
{
  __shared__ float Ar[4096], Ai[4096], Tr[4096], Ti[4096];
  __shared__ float twc[64], tws[64];
  int plane = blockIdx.x; int b = plane >> 7, c = plane & 127;
  int t = threadIdx.x;
  if (t < 64) {
    float ang = PI2 * (float)t / 64.0f;
    twc[t] = cosf(ang); tws[t] = sinf(ang);
  }
  size_t ibase = (size_t)b * 4096 * 128 + c;
  for (int i = t; i < 4096; i += 256) {
    Ar[i] = Or_[ibase + (size_t)i * 128];
    Ai[i] = Oi_[ibase + (size_t)i * 128];
  }
  __syncthreads();
  for (int j = 0; j < 16; j++) {
    int o = t + 256 * j; int hp = o >> 6, w = o & 63;
    float tr = 0.f, ti = 0.f;
    for (int wp = 0; wp < 64; wp++) {
      int k = (wp * w) & 63;
      float cr = twc[k], ci = tws[k];
      float ar = Ar[hp * 64 + wp], ai = Ai[hp * 64 + wp];
      tr += ar * cr - ai * ci;
      ti += ai * cr + ar * ci;
    }
    Tr[hp * 64 + w] = tr; Ti[hp * 64 + w] = ti;
  }
  __syncthreads();
  size_t obase = ((size_t)plane) << 12;
  for (int j = 0; j < 16; j++) {
    int o = t + 256 * j; int h = o >> 6, w = o & 63;
    float acc = 0.f;
    for (int hp = 0; hp < 64; hp++) {
      int k = (hp * h) & 63;
      acc += Tr[hp * 64 + w] * twc[k] - Ti[hp * 64 + w] * tws[k];
    }
    out[obase + o] = acc * (1.0f / 4096.0f);
  }
}

extern "C" void kernel_launch(void* const* d_in, const int* in_sizes, int n_in,
                              void* d_out, int out_size, void* d_ws, size_t ws_size,
                              hipStream_t stream) {
  const float* x   = (const float*)d_in[0];
  const float* y   = (const float*)d_in[1];
  const float* Wqr = (const float*)d_in[2];  const float* bqr = (const float*)d_in[3];
  const float* Wqi = (const float*)d_in[4];  const float* bqi = (const float*)d_in[5];
  const float* Wkr = (const float*)d_in[6];  const float* bkr = (const float*)d_in[7];
  const float* Wki = (const float*)d_in[8];  const float* bki = (const float*)d_in[9];
  const float* Wvr = (const float*)d_in[10]; const float* bvr = (const float*)d_in[11];
  const float* Wvi = (const float*)d_in[12]; const float* bvi = (const float*)d_in[13];
  char* wsb = (char*)d_ws;
  if (ws_size < ((size_t)40 << 20)) return;  // need 40 MiB
  unsigned short* FQ  = (unsigned short*)(wsb);                      // [0,8M)
  unsigned short* FK  = (unsigned short*)(wsb + ((size_t)8  << 20)); // [8,16M)
  unsigned short* FV  = (unsigned short*)(wsb + ((size_t)16 << 20)); // [16,20M)
  float* xr = (float*)(wsb + ((size_t)20 << 20));
  float* xi = (float*)(wsb + ((size_t)24 << 20));
  float* yr = (float*)(wsb + ((size_t)28 << 20));
  float* yi = (float*)(wsb + ((size_t)32 << 20));
  unsigned short* Kpk = (unsigned short*)(wsb + ((size_t)28 << 20)); // overlay dead yr/yi
  unsigned short* Vpk = (unsigned short*)(wsb + ((size_t)36 << 20)); // [36,40M)
  float* Or_ = (float*)(wsb + ((size_t)20 << 20));  // overlay dead xr
  float* Oi_ = (float*)(wsb + ((size_t)24 << 20));  // overlay dead xi
  float* out = (float*)d_out;

  hipLaunchKernelGGL(dft2_fwd_kernel, dim3(512), dim3(256), 0, stream,
                     x, y, xr, xi, yr, yi);
  hipLaunchKernelGGL(proj_kernel, dim3(64, 3, 2), dim3(256), 0, stream,
                     xr, xi, yr, yi,
                     Wqr, bqr, Wqi, bqi, Wkr, bkr, Wki, bki, Wvr, bvr, Wvi, bvi,
                     FQ, FK, FV);
  hipLaunchKernelGGL(kpack_kernel, dim3(128), dim3(256), 0, stream, FK, Kpk);
  hipLaunchKernelGGL(vpack_kernel, dim3(256), dim3(256), 0, stream, FV, Vpk);
  hipLaunchKernelGGL(attn_mfma_kernel, dim3(512), dim3(256), 0, stream,
                     FQ, (const short*)Kpk, (const short*)Vpk, Or_, Oi_);
  hipLaunchKernelGGL(idft2_kernel, dim3(256), dim3(256), 0, stream,
                     Or_, Oi_, out);
}